// Round 11
// baseline (83.667 us; speedup 1.0000x reference)
//
#include <hip/hip_runtime.h>
#include <math.h>

#define NSTEP 69
#define OBS 8

typedef float f32x2 __attribute__((ext_vector_type(2)));

namespace {

constexpr float kDT = 60.0f / 69.0f;

struct ETab { float lo[NSTEP]; float mid[NSTEP]; float hi[NSTEP]; };

constexpr float interp_e(float t) {
    constexpr float DTm[16] = {0.f,2.f,4.f,6.f,8.f,10.f,12.f,14.f,16.f,18.f,20.f,25.f,30.f,40.f,50.f,60.f};
    constexpr float EP[16]  = {0.01713f,0.145f,0.2442f,0.7659f,1.0f,0.8605f,0.7829f,0.5705f,
                               0.6217f,0.331f,0.3388f,0.3116f,0.05062f,0.02504f,0.01163f,0.01163f};
    if (t >= 60.0f) return EP[15];
    if (t <= 0.0f)  return EP[0];
    int k = 0;
    for (int m = 0; m < 15; m++) if (t >= DTm[m]) k = m;
    float u = (t - DTm[k]) / (DTm[k + 1] - DTm[k]);
    return EP[k] + u * (EP[k + 1] - EP[k]);
}

constexpr ETab make_etab() {
    ETab e{};
    for (int s = 0; s < NSTEP; s++) {
        float t0 = (float)s * kDT;
        e.lo[s]  = interp_e(t0);
        e.mid[s] = interp_e(t0 + 0.5f * kDT);
        e.hi[s]  = interp_e(t0 + kDT);
    }
    return e;
}

constexpr ETab ETAB = make_etab();   // literals under full unroll

} // namespace

// Single-lane, w-space chain (w_i = r*q_i):
//   specials x0,x1,x2 (scalar)
//   chain pairs W0=(w_q1,w_q5) W1=(w_q2,w_q6) W2=(w_q3,w_q7) W3=(w_q4,w_out)
//   prev(W0) = (r*x2, W3.x); chain derivs = pure subtracts in w-units
//   (r folds into stage constants); out-feedback k2*out = k2r*W3.y.
struct Dv { float d0, d1, d2; f32x2 G0, G1, G2, G3; };

__global__ __launch_bounds__(256) void stats5_kernel(
    const float* __restrict__ params,
    const float* __restrict__ design,
    const float* __restrict__ noise,
    float* __restrict__ out,
    int B)
{
    int b = blockIdx.x * blockDim.x + threadIdx.x;
    if (b >= B) return;

    // ---- issue ALL global loads first: params + noise latency overlaps the
    // design-readout + erfcf prologue math instead of serializing with it.
    long long base = (long long)b * 16;
    long long nb   = (long long)B * 16;
    float p0 = params[3 * b], p1 = params[3 * b + 1], p2 = params[3 * b + 2];
    const float4* nz = (const float4*)(noise + base);
    float4 n0 = nz[0], n1 = nz[1], n2 = nz[2], n3 = nz[3];

    // ---- design readout (wave-uniform -> SGPR)
    int ij[OBS], ij1[OBS]; float wj[OBS], w1j[OBS];
    #pragma unroll
    for (int j = 0; j < OBS; j++) {
        float pos = design[j] * (1.0f / kDT);
        int i = (int)pos;
        i = i < 0 ? 0 : (i > NSTEP - 1 ? NSTEP - 1 : i);
        float w = pos - (float)i;
        ij[j]  = __builtin_amdgcn_readfirstlane(i);
        ij1[j] = ij[j] + 1;
        int wb = __builtin_amdgcn_readfirstlane(__float_as_int(w));
        wj[j]  = __int_as_float(wb);
        w1j[j] = 1.0f - wj[j];
    }

    unsigned long long m_lo = 0ull, m_hi = 0ull;
    #pragma unroll
    for (int j = 0; j < OBS; j++) {
        if (ij[j]  < 64) m_lo |= 1ull << ij[j];  else m_hi |= 1ull << (ij[j]  - 64);
        if (ij1[j] < 64) m_lo |= 1ull << ij1[j]; else m_hi |= 1ull << (ij1[j] - 64);
    }

    // ---- parameter transform
    const float INV_SQRT2 = 0.7071067811865476f;
    float k1  = fmaf(0.5f * erfcf(-p0 * INV_SQRT2), 2.5f,  0.5f);
    float k2  = fmaf(0.5f * erfcf(-p1 * INV_SQRT2), 0.15f, 0.05f);
    float tau = fmaf(0.5f * erfcf(-p2 * INV_SQRT2), 6.0f,  4.0f);
    float r   = 8.0f / tau;

    const float hdt  = 0.5f * kDT;
    const float c6   = kDT * (1.0f / 6.0f);
    const float k2r  = 0.125f * k2 * tau;          // k2 / r (no division)
    const f32x2 crh2 = {hdt * r, hdt * r};
    const f32x2 crf2 = {kDT * r, kDT * r};
    const f32x2 c6r2 = {c6 * r, c6 * r};

    float a12[OBS], a0[OBS], b12[OBS], b0[OBS];
    #pragma unroll
    for (int j = 0; j < OBS; j++) { a12[j] = 0.f; a0[j] = 0.f; b12[j] = 0.f; b0[j] = 0.f; }

    float x0 = 3.71f, x1 = 0.f, x2 = 0.f;
    f32x2 W0 = {0.f, 0.f}, W1 = W0, W2 = W0, W3 = W0;

    if (m_lo & 1ull) {
        #pragma unroll
        for (int j = 0; j < OBS; j++)
            if (ij[j] == 0) { a12[j] = 0.f; a0[j] = 3.71f; }
    }

    auto DERIV = [&](float k1E, float X0, float X1, float X2,
                     const f32x2& V0, const f32x2& V1, const f32x2& V2, const f32x2& V3) {
        Dv d;
        float a  = k1E * X0;
        float sq = X1 * X1;
        d.d0 = fmaf(k2r, V3.y, -a);
        d.d1 = a - sq;
        d.d2 = fmaf(-k2, X2, sq);
        f32x2 s0; s0.x = r * X2; s0.y = V3.x;
        d.G0 = s0 - V0;
        d.G1 = V0 - V1;
        d.G2 = V1 - V2;
        d.G3 = V2 - V3;
        return d;
    };

    #pragma unroll
    for (int s = 0; s < NSTEP; s++) {
        const float ea = ETAB.lo[s], eb = ETAB.mid[s], ec = ETAB.hi[s];
        float k1a = k1 * ea, k1b = k1 * eb, k1c = k1 * ec;

        float t0, t1, t2; f32x2 U0, U1, U2, U3;

        Dv d1 = DERIV(k1a, x0, x1, x2, W0, W1, W2, W3);
        t0 = fmaf(hdt, d1.d0, x0); t1 = fmaf(hdt, d1.d1, x1); t2 = fmaf(hdt, d1.d2, x2);
        U0 = crh2 * d1.G0 + W0; U1 = crh2 * d1.G1 + W1;
        U2 = crh2 * d1.G2 + W2; U3 = crh2 * d1.G3 + W3;

        Dv d2 = DERIV(k1b, t0, t1, t2, U0, U1, U2, U3);
        t0 = fmaf(hdt, d2.d0, x0); t1 = fmaf(hdt, d2.d1, x1); t2 = fmaf(hdt, d2.d2, x2);
        U0 = crh2 * d2.G0 + W0; U1 = crh2 * d2.G1 + W1;
        U2 = crh2 * d2.G2 + W2; U3 = crh2 * d2.G3 + W3;

        Dv d3 = DERIV(k1b, t0, t1, t2, U0, U1, U2, U3);
        t0 = fmaf(kDT, d3.d0, x0); t1 = fmaf(kDT, d3.d1, x1); t2 = fmaf(kDT, d3.d2, x2);
        U0 = crf2 * d3.G0 + W0; U1 = crf2 * d3.G1 + W1;
        U2 = crf2 * d3.G2 + W2; U3 = crf2 * d3.G3 + W3;

        Dv d4 = DERIV(k1c, t0, t1, t2, U0, U1, U2, U3);

        float u;
        u = fmaf(2.0f, d2.d0 + d3.d0, d1.d0 + d4.d0); x0 = fmaf(c6, u, x0);
        u = fmaf(2.0f, d2.d1 + d3.d1, d1.d1 + d4.d1); x1 = fmaf(c6, u, x1);
        u = fmaf(2.0f, d2.d2 + d3.d2, d1.d2 + d4.d2); x2 = fmaf(c6, u, x2);
        f32x2 two = {2.0f, 2.0f}, v;
        v = two * (d2.G0 + d3.G0) + (d1.G0 + d4.G0); W0 = c6r2 * v + W0;
        v = two * (d2.G1 + d3.G1) + (d1.G1 + d4.G1); W1 = c6r2 * v + W1;
        v = two * (d2.G2 + d3.G2) + (d1.G2 + d4.G2); W2 = c6r2 * v + W2;
        v = two * (d2.G3 + d3.G3) + (d1.G3 + d4.G3); W3 = c6r2 * v + W3;

        const int ti = s + 1;
        unsigned long long mm = (ti < 64) ? (m_lo >> ti) : (m_hi >> (ti - 64));
        if (__builtin_expect((int)(mm & 1ull), 0)) {
            float s12 = x1 + x2;
            #pragma unroll
            for (int j = 0; j < OBS; j++) {
                if (ti == ij[j])  { a12[j] = s12; a0[j] = x0; }
                if (ti == ij1[j]) { b12[j] = s12; b0[j] = x0; }
            }
        }
    }

    float o1[OBS], o2[OBS];
    #pragma unroll
    for (int j = 0; j < OBS; j++) {
        o1[j] = 0.33f * fmaf(w1j[j], a12[j], wj[j] * b12[j]);
        o2[j] = 0.26f * fmaf(w1j[j], a0[j] + a12[j], wj[j] * (b0[j] + b12[j]));
    }

    float4* outv = (float4*)(out + base);
    float4* outn = (float4*)(out + nb + base);

    float4 v0 = make_float4(o1[0], o1[1], o1[2], o1[3]);
    float4 v1 = make_float4(o1[4], o1[5], o1[6], o1[7]);
    float4 v2 = make_float4(o2[0], o2[1], o2[2], o2[3]);
    float4 v3 = make_float4(o2[4], o2[5], o2[6], o2[7]);
    outv[0] = v0; outv[1] = v1; outv[2] = v2; outv[3] = v3;

    outn[0] = make_float4(fmaf(0.01f, n0.x, v0.x), fmaf(0.01f, n0.y, v0.y),
                          fmaf(0.01f, n0.z, v0.z), fmaf(0.01f, n0.w, v0.w));
    outn[1] = make_float4(fmaf(0.01f, n1.x, v1.x), fmaf(0.01f, n1.y, v1.y),
                          fmaf(0.01f, n1.z, v1.z), fmaf(0.01f, n1.w, v1.w));
    outn[2] = make_float4(fmaf(0.01f, n2.x, v2.x), fmaf(0.01f, n2.y, v2.y),
                          fmaf(0.01f, n2.z, v2.z), fmaf(0.01f, n2.w, v2.w));
    outn[3] = make_float4(fmaf(0.01f, n3.x, v3.x), fmaf(0.01f, n3.y, v3.y),
                          fmaf(0.01f, n3.z, v3.z), fmaf(0.01f, n3.w, v3.w));
}

extern "C" void kernel_launch(void* const* d_in, const int* in_sizes, int n_in,
                              void* d_out, int out_size, void* d_ws, size_t ws_size,
                              hipStream_t stream) {
    const float* params = (const float*)d_in[0];
    const float* design = (const float*)d_in[1];
    const float* noise  = (const float*)d_in[2];
    float* out = (float*)d_out;
    int B = in_sizes[0] / 3;
    int block = 256;
    int grid = (B + block - 1) / block;
    stats5_kernel<<<grid, block, 0, stream>>>(params, design, noise, out, B);
}